// Round 2
// baseline (6383.672 us; speedup 1.0000x reference)
//
#include <hip/hip_runtime.h>
#include <cstdint>
#include <cstddef>

#define B_ 128
#define P_ 196
#define ENC_ 2048
#define A_ 512
#define E_ 512
#define D_ 512
#define V_ 10000
#define L_ 52
#define T_ 51

using short8 = __attribute__((ext_vector_type(8))) short;
using short4v = __attribute__((ext_vector_type(4))) short;
using floatx4 = __attribute__((ext_vector_type(4))) float;

__device__ __forceinline__ float sigf(float x){ return 1.f/(1.f+expf(-x)); }

__device__ __forceinline__ unsigned short f2bf(float f){
  unsigned int u = __float_as_uint(f);
  unsigned int r = (u + 0x7fffu + ((u >> 16) & 1u)) >> 16;
  return (unsigned short)r;
}
__device__ __forceinline__ float bf2f(unsigned short u){
  return __uint_as_float(((unsigned int)u) << 16);
}

// interleaved gate-column mapping: col cc in [0,2048) <-> (d, gate)
// d = ((cc>>7)<<5) | (((cc>>6)&1)<<4) | (cc&15) ; gate = (cc>>4)&3
// original gate row = gate*512 + d
__device__ __forceinline__ int ild_d(int cc){ return ((cc>>7)<<5) | (((cc>>6)&1)<<4) | (cc&15); }
__device__ __forceinline__ int ild_gate(int cc){ return (cc>>4)&3; }

// ---------------- sort (stable descending by length) ----------------
__global__ void sort_kernel(const int* __restrict__ cap_len, const int* __restrict__ caps,
                            int* __restrict__ order, int* __restrict__ dec_len,
                            int* __restrict__ caps_sorted,
                            float* __restrict__ out_caps, float* __restrict__ out_declen){
  __shared__ int len_s[B_];
  int i = threadIdx.x;
  len_s[i] = cap_len[i];
  __syncthreads();
  int li = len_s[i];
  int pos = 0;
  for (int j = 0; j < B_; j++){
    int lj = len_s[j];
    pos += (lj > li) || (lj == li && j < i);
  }
  order[pos] = i;
  dec_len[pos] = li - 1;
  out_declen[pos] = (float)(li - 1);
  for (int l = 0; l < L_; l++){
    int v = caps[i * L_ + l];
    caps_sorted[pos * L_ + l] = v;
    out_caps[pos * L_ + l] = (float)v;
  }
}

// ---------------- enc gather + fp32->bf16 ----------------
__global__ void gather_kernel(const float* __restrict__ enc, const int* __restrict__ order,
                              unsigned short* __restrict__ enc_s){
  int b = blockIdx.y;
  int i = (blockIdx.x * 256 + threadIdx.x) * 4;
  const float4 v = *(const float4*)(enc + (size_t)order[b] * (P_ * ENC_) + i);
  short4v r;
  r[0] = (short)f2bf(v.x); r[1] = (short)f2bf(v.y);
  r[2] = (short)f2bf(v.z); r[3] = (short)f2bf(v.w);
  *(short4v*)(enc_s + (size_t)b * (P_ * ENC_) + i) = r;
}

// ---------------- weight conversion/packing + state init ----------------
__global__ void prep_kernel(const float* __restrict__ We, const float* __restrict__ Wd,
                            const float* __restrict__ Wbeta,
                            const float* __restrict__ W_ih, const float* __restrict__ W_hh,
                            const float* __restrict__ Wfc,
                            const float* __restrict__ bd, const float* __restrict__ bbeta,
                            const float* __restrict__ b_ih, const float* __restrict__ b_hh,
                            unsigned short* __restrict__ We_b, unsigned short* __restrict__ Wpre2_b,
                            unsigned short* __restrict__ WgA_b, unsigned short* __restrict__ Wfc_b,
                            float* __restrict__ bias2,
                            float* __restrict__ h, float* __restrict__ c,
                            unsigned short* __restrict__ h_b){
  unsigned int idx = blockIdx.x * blockDim.x + threadIdx.x;
  unsigned int stride = gridDim.x * blockDim.x;
  // We_b: 512x2048 direct
  for (unsigned int i = idx; i < 512u * 2048u; i += stride) We_b[i] = f2bf(We[i]);
  // Wpre2_b rows: [Wd(512) | Wbeta(2048) | W_hh interleaved(2048)] x K=512
  for (unsigned int i = idx; i < 4608u * 512u; i += stride){
    unsigned int row = i >> 9, k = i & 511u;
    float v;
    if (row < 512u) v = Wd[row * 512u + k];
    else if (row < 2560u) v = Wbeta[(row - 512u) * 512u + k];
    else {
      int cc = (int)row - 2560;
      int orig = ild_gate(cc) * 512 + ild_d(cc);
      v = W_hh[(size_t)orig * 512u + k];
    }
    Wpre2_b[i] = f2bf(v);
  }
  // WgA_b: interleaved rows (2048) x K=2560 (full W_ih row: [emb 512 | awe 2048])
  for (unsigned int i = idx; i < 2048u * 2560u; i += stride){
    unsigned int row = i / 2560u, k = i - row * 2560u;
    int orig = ild_gate((int)row) * 512 + ild_d((int)row);
    WgA_b[i] = f2bf(W_ih[(size_t)orig * 2560u + k]);
  }
  // Wfc_b: 10000x512 direct
  for (unsigned int i = idx; i < 10000u * 512u; i += stride) Wfc_b[i] = f2bf(Wfc[i]);
  // bias2: [bd(512) | bbeta(2048) | (b_ih+b_hh) interleaved(2048)]
  for (unsigned int i = idx; i < 4608u; i += stride){
    float v;
    if (i < 512u) v = bd[i];
    else if (i < 2560u) v = bbeta[i - 512u];
    else {
      int cc = (int)i - 2560;
      int orig = ild_gate(cc) * 512 + ild_d(cc);
      v = b_ih[orig] + b_hh[orig];
    }
    bias2[i] = v;
  }
  // state init
  for (unsigned int i = idx; i < (unsigned)B_ * D_; i += stride){
    h[i] = 0.f; c[i] = 0.f; h_b[i] = 0;
  }
}

// ---------------- shared GEMM mainloop: C(128x128) = A(MxK) @ B(NxK)^T ----------------
// requires: __shared__ unsigned short As[128*32], Bs[128*32]; int m0, n0 defined.
// defines: tid, lane, w, mbase, nbase, fr, fk, acc[4][4]
#define GEMM_CORE(Aptr, LDA, Bptr, LDB, KDIM, NCLAMP)                         \
  int tid = threadIdx.x; int lane = tid & 63; int w = tid >> 6;               \
  const floatx4 vzero = {0.f,0.f,0.f,0.f};                                    \
  floatx4 acc[4][4];                                                          \
  _Pragma("unroll") for (int i_=0;i_<4;i_++)                                  \
  _Pragma("unroll") for (int j_=0;j_<4;j_++) acc[i_][j_]=vzero;               \
  int mbase=(w&1)<<6, nbase=(w>>1)<<6;                                        \
  int fr=lane&15, fk=(lane>>4)<<3;                                            \
  for (int k0=0;k0<(KDIM);k0+=32){                                            \
    _Pragma("unroll") for (int r_=0;r_<2;r_++){                               \
      int chunk=r_*256+tid; int row=chunk>>2, kc=(chunk&3)<<3;                \
      short8 av=*(const short8*)((Aptr)+(size_t)(m0+row)*(LDA)+k0+kc);        \
      int bn=n0+row; if(bn>(NCLAMP)) bn=(NCLAMP);                             \
      short8 bv=*(const short8*)((Bptr)+(size_t)bn*(LDB)+k0+kc);              \
      *(short8*)&As[chunk*8]=av; *(short8*)&Bs[chunk*8]=bv; }                 \
    __syncthreads();                                                          \
    short8 af[4], bfrag[4];                                                   \
    _Pragma("unroll") for (int i_=0;i_<4;i_++){                               \
      af[i_]=*(const short8*)&As[(mbase+i_*16+fr)*32+fk];                     \
      bfrag[i_]=*(const short8*)&Bs[(nbase+i_*16+fr)*32+fk]; }                \
    _Pragma("unroll") for (int mi_=0;mi_<4;mi_++)                             \
    _Pragma("unroll") for (int ni_=0;ni_<4;ni_++)                             \
      acc[mi_][ni_]=__builtin_amdgcn_mfma_f32_16x16x32_bf16(af[mi_],bfrag[ni_],acc[mi_][ni_],0,0,0); \
    __syncthreads(); }

// ---------------- enc_att = enc_s @ We^T + be -> bf16 ----------------
__launch_bounds__(256)
__global__ void gemm_encatt(const unsigned short* __restrict__ A,
                            const unsigned short* __restrict__ Bm,
                            const float* __restrict__ bias,
                            unsigned short* __restrict__ Cb){
  __shared__ unsigned short As[128*32];
  __shared__ unsigned short Bs[128*32];
  int m0 = blockIdx.y * 128, n0 = blockIdx.x * 128;
  GEMM_CORE(A, ENC_, Bm, ENC_, ENC_, 511)
#pragma unroll
  for (int mi = 0; mi < 4; mi++)
#pragma unroll
    for (int ni = 0; ni < 4; ni++){
      int col = n0 + nbase + ni*16 + fr;
      float bb = bias[col];
      int rb = m0 + mbase + mi*16 + ((lane>>4)<<2);
#pragma unroll
      for (int r = 0; r < 4; r++)
        Cb[(size_t)(rb + r) * A_ + col] = f2bf(acc[mi][ni][r] + bb);
    }
}

// ---------------- K1: out_pre / ginit = h @ [Wd;Wbeta;Whh_i]^T + bias2 ----------------
__launch_bounds__(256)
__global__ void gemm_pre2(const unsigned short* __restrict__ A,      // h_b 128x512
                          const unsigned short* __restrict__ Bm,     // Wpre2_b 4608x512
                          const float* __restrict__ bias2,
                          float* __restrict__ out_pre,               // 128x2560
                          float* __restrict__ ginit){                // 128x2048 (interleaved)
  __shared__ unsigned short As[128*32];
  __shared__ unsigned short Bs[128*32];
  int m0 = 0, n0 = blockIdx.x * 128;
  GEMM_CORE(A, D_, Bm, D_, D_, 4607)
#pragma unroll
  for (int mi = 0; mi < 4; mi++)
#pragma unroll
    for (int ni = 0; ni < 4; ni++){
      int col = n0 + nbase + ni*16 + fr;
      float bb = bias2[col];
      int rb = mbase + mi*16 + ((lane>>4)<<2);
#pragma unroll
      for (int r = 0; r < 4; r++){
        float v = acc[mi][ni][r] + bb;
        int b = rb + r;
        if (col < 2560) out_pre[(size_t)b * 2560 + col] = v;
        else            ginit[(size_t)b * 2048 + (col - 2560)] = v;
      }
    }
}

// ---------------- fused attention: scores + softmax + awe + gate -> axh ----------------
// grid (2, 128) x 1024 threads
__launch_bounds__(1024)
__global__ void attn_kernel(const unsigned short* __restrict__ enc_att,
                            const unsigned short* __restrict__ enc_s,
                            const float* __restrict__ out_pre,
                            const float* __restrict__ wf, const float* __restrict__ bfp,
                            const float* __restrict__ emb, const int* __restrict__ caps_sorted,
                            unsigned short* __restrict__ axh,   // [b][2560] = [emb | gate*awe]
                            int t){
  __shared__ float sc[P_];
  __shared__ float al[P_];
  __shared__ float red[256];
  __shared__ float4 part[4][256];
  int b = blockIdx.y, bx = blockIdx.x, tid = threadIdx.x;

  // ---- phase 1: scores ----
  int wid = tid >> 6, lane = tid & 63;
  float dav[8], wfv[8];
  {
    const float* dp = out_pre + (size_t)b * 2560 + lane * 8;
    *(float4*)&dav[0] = *(const float4*)(dp);
    *(float4*)&dav[4] = *(const float4*)(dp + 4);
    *(float4*)&wfv[0] = *(const float4*)(wf + lane * 8);
    *(float4*)&wfv[4] = *(const float4*)(wf + lane * 8 + 4);
  }
  float bfv = bfp[0];
  for (int p = wid; p < P_; p += 16){
    short8 e = *(const short8*)(enc_att + ((size_t)b * P_ + p) * A_ + lane * 8);
    float s = 0.f;
#pragma unroll
    for (int j = 0; j < 8; j++){
      float v = bf2f((unsigned short)e[j]) + dav[j];
      s += fmaxf(v, 0.f) * wfv[j];
    }
#pragma unroll
    for (int off = 32; off > 0; off >>= 1) s += __shfl_down(s, off);
    if (lane == 0) sc[p] = s + bfv;
  }
  __syncthreads();

  // ---- phase 2: softmax over 196 ----
  if (tid < 256) red[tid] = (tid < P_) ? sc[tid] : -1e30f;
  __syncthreads();
  for (int s = 128; s > 0; s >>= 1){ if (tid < s) red[tid] = fmaxf(red[tid], red[tid + s]); __syncthreads(); }
  float mx = red[0];
  __syncthreads();
  float ex = 0.f;
  if (tid < 256){ ex = (tid < P_) ? expf(sc[tid] - mx) : 0.f; red[tid] = ex; }
  __syncthreads();
  for (int s = 128; s > 0; s >>= 1){ if (tid < s) red[tid] += red[tid + s]; __syncthreads(); }
  float inv = 1.f / red[0];
  if (tid < P_) al[tid] = ex * inv;
  __syncthreads();

  // ---- phase 3: awe with 4-way p split ----
  int pg = tid >> 8, et = tid & 255;
  int e0 = bx * 1024 + et * 4;
  const unsigned short* encb = enc_s + (size_t)b * (P_ * ENC_) + e0;
  float a0 = 0.f, a1 = 0.f, a2 = 0.f, a3 = 0.f;
  int pbeg = pg * 49;
#pragma unroll 7
  for (int p = pbeg; p < pbeg + 49; p++){
    float a = al[p];
    short4v v = *(const short4v*)(encb + (size_t)p * ENC_);
    a0 += a * bf2f((unsigned short)v[0]);
    a1 += a * bf2f((unsigned short)v[1]);
    a2 += a * bf2f((unsigned short)v[2]);
    a3 += a * bf2f((unsigned short)v[3]);
  }
  float4 pv; pv.x = a0; pv.y = a1; pv.z = a2; pv.w = a3;
  part[pg][et] = pv;
  __syncthreads();
  if (pg == 0){
    float4 s0 = part[0][et], s1 = part[1][et], s2 = part[2][et], s3 = part[3][et];
    float4 g4 = *(const float4*)(out_pre + (size_t)b * 2560 + 512 + e0);
    short4v r;
    r[0] = (short)f2bf(sigf(g4.x) * (s0.x + s1.x + s2.x + s3.x));
    r[1] = (short)f2bf(sigf(g4.y) * (s0.y + s1.y + s2.y + s3.y));
    r[2] = (short)f2bf(sigf(g4.z) * (s0.z + s1.z + s2.z + s3.z));
    r[3] = (short)f2bf(sigf(g4.w) * (s0.w + s1.w + s2.w + s3.w));
    *(short4v*)(axh + (size_t)b * 2560 + 512 + e0) = r;
  }
  // emb gather for this step's token into axh[:512]
  if (bx == 1 && tid < 512){
    int tok = caps_sorted[b * L_ + t];
    axh[(size_t)b * 2560 + tid] = f2bf(emb[(size_t)tok * E_ + tid]);
  }
}

// ---------------- K3: gates GEMM + fused LSTM epilogue ----------------
// gates[b][cc] = (axh @ WgA^T)[b][cc] + ginit[b][cc]; cc interleaved (d,gate)
__launch_bounds__(256)
__global__ void gemm_gates_lstm(const unsigned short* __restrict__ A,    // axh 128x2560
                                const unsigned short* __restrict__ Bm,   // WgA_b 2048x2560
                                const float* __restrict__ ginit,         // 128x2048
                                float* __restrict__ h, float* __restrict__ c,
                                unsigned short* __restrict__ h_b,
                                unsigned short* __restrict__ hnew_b,
                                const int* __restrict__ dec_len, int t){
  __shared__ unsigned short As[128*32];
  __shared__ unsigned short Bs[128*32];
  int m0 = 0, n0 = blockIdx.x * 128;
  GEMM_CORE(A, 2560, Bm, 2560, 2560, 2047)
  int colbase = n0 + nbase;
  int d = ((colbase>>7)<<5) | (((colbase>>6)&1)<<4) | fr;
#pragma unroll
  for (int mi = 0; mi < 4; mi++){
#pragma unroll
    for (int r = 0; r < 4; r++){
      int b = mbase + mi*16 + ((lane>>4)<<2) + r;
      const float* gi = ginit + (size_t)b * 2048 + colbase + fr;
      float iv = acc[mi][0][r] + gi[0];
      float fv = acc[mi][1][r] + gi[16];
      float gv = acc[mi][2][r] + gi[32];
      float ov = acc[mi][3][r] + gi[48];
      int idx = b * 512 + d;
      float cold = c[idx];
      float cn = sigf(fv) * cold + sigf(iv) * tanhf(gv);
      float hn = sigf(ov) * tanhf(cn);
      bool act = t < dec_len[b];
      float hv = act ? hn : h[idx];
      float cv = act ? cn : cold;
      h[idx] = hv; c[idx] = cv;
      h_b[idx] = f2bf(hv);
      hnew_b[(size_t)t * (B_ * D_) + idx] = f2bf(hn);
    }
  }
}

// ---------------- preds GEMM with LDS-staged coalesced epilogue ----------------
// C(6528x10000) = hnew_b @ Wfc_b^T + bfc, masked + scattered to (B,T,V)
__launch_bounds__(256)
__global__ void gemm_preds(const unsigned short* __restrict__ A,    // hnew_b 6528x512
                           const unsigned short* __restrict__ Bm,   // Wfc_b 10000x512
                           const float* __restrict__ bias,
                           float* __restrict__ Cf,
                           const int* __restrict__ dec_len){
  __shared__ __attribute__((aligned(16))) char smem[4 * 64 * 68 * 4];
  unsigned short* As = (unsigned short*)smem;
  unsigned short* Bs = (unsigned short*)(smem + 8192);
  int m0 = blockIdx.y * 128, n0 = blockIdx.x * 128;
  GEMM_CORE(A, D_, Bm, D_, D_, V_ - 1)
  // stage per-wave 64x64 quadrant into LDS (stride 68 floats, 16B-aligned rows)
  float* Cs = (float*)smem + (size_t)w * (64 * 68);
#pragma unroll
  for (int mi = 0; mi < 4; mi++)
#pragma unroll
    for (int ni = 0; ni < 4; ni++){
      int lc = ni*16 + fr;
      int col = n0 + nbase + lc;
      float bb = bias[col < V_ ? col : V_ - 1];
#pragma unroll
      for (int r = 0; r < 4; r++){
        int lr = mi*16 + ((lane>>4)<<2) + r;
        Cs[lr * 68 + lc] = acc[mi][ni][r] + bb;
      }
    }
  // write out: 16-lane groups write 256B-contiguous row segments
#pragma unroll
  for (int rd = 0; rd < 16; rd++){
    int lr = rd * 4 + (lane >> 4);
    int m = m0 + mbase + lr;
    int tt = m >> 7, b = m & 127;
    int col = n0 + nbase + fr * 4;
    floatx4 v = *(const floatx4*)&Cs[lr * 68 + fr * 4];
    if (tt >= dec_len[b]){ v[0]=0.f; v[1]=0.f; v[2]=0.f; v[3]=0.f; }
    if (col < V_)
      __builtin_nontemporal_store(v, (floatx4*)(Cf + ((size_t)b * T_ + tt) * V_ + col));
  }
}

extern "C" void kernel_launch(void* const* d_in, const int* in_sizes, int n_in,
                              void* d_out, int out_size, void* d_ws, size_t ws_size,
                              hipStream_t stream) {
  const float* encoder_out = (const float*)d_in[0];
  const int*   caps        = (const int*)d_in[1];
  const int*   cap_len     = (const int*)d_in[2];
  const float* emb         = (const float*)d_in[3];
  const float* We          = (const float*)d_in[4];
  const float* be          = (const float*)d_in[5];
  const float* Wd          = (const float*)d_in[6];
  const float* bd          = (const float*)d_in[7];
  const float* wf          = (const float*)d_in[8];
  const float* bf          = (const float*)d_in[9];
  const float* W_ih        = (const float*)d_in[10];
  const float* b_ih        = (const float*)d_in[11];
  const float* W_hh        = (const float*)d_in[12];
  const float* b_hh        = (const float*)d_in[13];
  const float* Wbeta       = (const float*)d_in[14];
  const float* bbeta       = (const float*)d_in[15];
  const float* Wfc         = (const float*)d_in[16];
  const float* bfc         = (const float*)d_in[17];

  float* out_preds  = (float*)d_out;
  float* out_caps   = out_preds + (size_t)B_ * T_ * V_;
  float* out_declen = out_caps + (size_t)B_ * L_;

  char* w = (char*)d_ws;
  auto alloc = [&](size_t bytes) -> void* {
    void* p = (void*)w;
    w += (bytes + 255) & ~(size_t)255;
    return p;
  };
  int*   order       = (int*)alloc(B_ * 4);
  int*   dec_len     = (int*)alloc(B_ * 4);
  int*   caps_sorted = (int*)alloc((size_t)B_ * L_ * 4);
  unsigned short* enc_s   = (unsigned short*)alloc((size_t)B_ * P_ * ENC_ * 2);
  unsigned short* We_b    = (unsigned short*)alloc((size_t)512 * 2048 * 2);
  unsigned short* Wpre2_b = (unsigned short*)alloc((size_t)4608 * 512 * 2);
  unsigned short* WgA_b   = (unsigned short*)alloc((size_t)2048 * 2560 * 2);
  unsigned short* Wfc_b   = (unsigned short*)alloc((size_t)10000 * 512 * 2);
  unsigned short* enc_att = (unsigned short*)alloc((size_t)B_ * P_ * A_ * 2);
  float* bias2       = (float*)alloc(4608 * 4);
  float* out_pre     = (float*)alloc((size_t)B_ * 2560 * 4);
  float* ginit       = (float*)alloc((size_t)B_ * 2048 * 4);
  unsigned short* axh = (unsigned short*)alloc((size_t)B_ * 2560 * 2);
  float* h           = (float*)alloc((size_t)B_ * D_ * 4);
  float* c           = (float*)alloc((size_t)B_ * D_ * 4);
  unsigned short* h_b = (unsigned short*)alloc((size_t)B_ * D_ * 2);
  unsigned short* hnew_b = (unsigned short*)alloc((size_t)T_ * B_ * D_ * 2);

  sort_kernel<<<1, 128, 0, stream>>>(cap_len, caps, order, dec_len, caps_sorted, out_caps, out_declen);
  gather_kernel<<<dim3(392, 128), 256, 0, stream>>>(encoder_out, order, enc_s);
  prep_kernel<<<2048, 256, 0, stream>>>(We, Wd, Wbeta, W_ih, W_hh, Wfc, bd, bbeta, b_ih, b_hh,
                                        We_b, Wpre2_b, WgA_b, Wfc_b, bias2, h, c, h_b);

  // enc_att = enc_s @ We^T + be -> bf16 : M=25088, N=512, K=2048
  gemm_encatt<<<dim3(4, 196), 256, 0, stream>>>(enc_s, We_b, be, enc_att);

  for (int t = 0; t < T_; t++){
    // K1: out_pre(2560) + ginit(2048) = h @ [Wd;Wbeta;Whh_i]^T + bias2
    gemm_pre2<<<36, 256, 0, stream>>>(h_b, Wpre2_b, bias2, out_pre, ginit);

    // K2: attention -> axh = [emb | gate*awe]
    attn_kernel<<<dim3(2, B_), 1024, 0, stream>>>(enc_att, enc_s, out_pre, wf, bf,
                                                  emb, caps_sorted, axh, t);

    // K3: gates = axh @ WgA^T + ginit, fused LSTM epilogue
    gemm_gates_lstm<<<16, 256, 0, stream>>>(axh, WgA_b, ginit, h, c, h_b, hnew_b, dec_len, t);
  }

  // preds: (T*B, V) = hnew @ Wfc^T + bfc, masked + scattered to (B,T,V)
  gemm_preds<<<dim3(79, 51), 256, 0, stream>>>(hnew_b, Wfc_b, bfc, out_preds, dec_len);
}